// Round 5
// baseline (628.236 us; speedup 1.0000x reference)
//
#include <hip/hip_runtime.h>
#include <hip/hip_bf16.h>

// Problem constants (from reference)
#define NNODES 10000
#define NEDGES 320000
#define INF_   1280
#define HID_   128
#define HEADS_ 4
#define OUTF_  500
#define HC_    512          // HEADS_*HID_
#define NEG_SLOPE 0.2f
#define BN_EPS 1e-5f

typedef __attribute__((ext_vector_type(8))) short short8x;
typedef __attribute__((ext_vector_type(4))) float f32x4;
typedef unsigned short ushort_t;
typedef unsigned int uint_t;

__device__ __forceinline__ ushort_t f2bf(float f) {
    uint_t u = __float_as_uint(f);
    u = (u + 0x7fffu + ((u >> 16) & 1u)) >> 16;   // round-to-nearest-even
    return (ushort_t)u;
}
__device__ __forceinline__ float bf_lo(uint_t p) { return __uint_as_float(p << 16); }
__device__ __forceinline__ float bf_hi(uint_t p) { return __uint_as_float(p & 0xffff0000u); }
__device__ __forceinline__ float lrelu(float x) { return (x >= 0.f) ? x : NEG_SLOPE * x; }

// ---------------------------------------------------------------------------
// utility kernels
// ---------------------------------------------------------------------------
__global__ void zero_kernel(float* __restrict__ p, size_t n) {
    size_t i = (size_t)blockIdx.x * blockDim.x + threadIdx.x;
    size_t stride = (size_t)gridDim.x * blockDim.x;
    for (; i < n; i += stride) p[i] = 0.0f;
}

__global__ void copy_int_kernel(const int* __restrict__ src, int* __restrict__ dst, int n) {
    int i = blockIdx.x * blockDim.x + threadIdx.x;
    if (i < n) dst[i] = src[i];
}

// fp32 -> bf16 (flat)
__global__ void conv_bf16_kernel(const float* __restrict__ in, ushort_t* __restrict__ out, int n) {
    int i = blockIdx.x * blockDim.x + threadIdx.x;
    if (i < n) out[i] = f2bf(in[i]);
}

// fp32 W[K][N] -> bf16 Wt[Npad][K]  (write-coalesced; rows [N,Npad) zeroed)
__global__ void transconv_kernel(const float* __restrict__ W, ushort_t* __restrict__ Wt,
                                 int K, int N, int Npad) {
    int i = blockIdx.x * blockDim.x + threadIdx.x;
    if (i < Npad * K) {
        int n = i / K;
        int k = i - n * K;
        Wt[i] = (n < N) ? f2bf(W[(size_t)k * N + n]) : (ushort_t)0;
    }
}

// ---------------------------------------------------------------------------
// CSR build (by destination) — edges are identical across layers, built once
// ---------------------------------------------------------------------------
__global__ void count_kernel(const int* __restrict__ dst, int* __restrict__ counts, int E) {
    int e = blockIdx.x * blockDim.x + threadIdx.x;
    if (e < E) atomicAdd(&counts[dst[e]], 1);
}

__global__ void scan_kernel(const int* __restrict__ counts, int* __restrict__ offsets, int n) {
    __shared__ int tmp[1024];
    int tid = threadIdx.x;
    int carry = 0;
    int nchunk = (n + 1023) / 1024;
    for (int ch = 0; ch < nchunk; ++ch) {
        int i = ch * 1024 + tid;
        int v = (i < n) ? counts[i] : 0;
        tmp[tid] = v;
        __syncthreads();
        for (int off = 1; off < 1024; off <<= 1) {
            int t = (tid >= off) ? tmp[tid - off] : 0;
            __syncthreads();
            tmp[tid] += t;
            __syncthreads();
        }
        if (i < n) offsets[i] = carry + tmp[tid] - v;  // exclusive scan
        carry += tmp[1023];
        __syncthreads();
    }
    if (tid == 0) offsets[n] = carry;
}

__global__ void scatter_kernel(const int* __restrict__ src, const int* __restrict__ dst,
                               int* __restrict__ cursor, int* __restrict__ esrc, int E) {
    int e = blockIdx.x * blockDim.x + threadIdx.x;
    if (e < E) {
        int p = atomicAdd(&cursor[dst[e]], 1);
        esrc[p] = src[e];
    }
}

// ---------------------------------------------------------------------------
// Direct-from-global bf16 MFMA GEMM (no LDS, no barriers):
//   C[M,Npad] = A[M,K] @ Bt[Npad,K]^T, written as bf16 with row stride Npad.
//   Fragments for mfma_f32_16x16x32_bf16 are 16B-contiguous in both A
//   (row-major [M][K]) and Bt ([N][K]), so each wave loads its fragments
//   straight from global (uint4) and issues MFMAs with no synchronization.
//   Block = 256 thr = 4 waves in 2x2; wave owns a 64x64 quadrant (4x4 MFMAs
//   per BK=32 step). 1-deep software pipeline: next-K frags load before
//   current MFMAs so the compiler emits fine-grained vmcnt waits.
//   A tail rows clamp to M-1 (stores masked); Npad must be mult of 128.
// ---------------------------------------------------------------------------
__global__ __launch_bounds__(256) void gemm_dg_kernel(
    const ushort_t* __restrict__ A,    // [M][K] bf16
    const ushort_t* __restrict__ Bt,   // [Npad][K] bf16 (transposed, padded)
    ushort_t* __restrict__ Cb,         // [M][Npad] bf16
    int M, int K, int Npad)
{
    int lane = threadIdx.x & 63;
    int w    = threadIdx.x >> 6;
    int quad = lane >> 4;
    int c16  = lane & 15;
    int m0 = blockIdx.y * 128 + (w & 1) * 64;
    int n0 = blockIdx.x * 128 + (w >> 1) * 64;

    // fragment base pointers (k0 = 0), per lane
    const ushort_t* arow[4];
    const ushort_t* brow[4];
#pragma unroll
    for (int t = 0; t < 4; ++t) {
        int rm = m0 + t * 16 + c16;
        if (rm > M - 1) rm = M - 1;           // clamp tail (masked at store)
        arow[t] = A + (size_t)rm * K + quad * 8;
        brow[t] = Bt + (size_t)(n0 + t * 16 + c16) * K + quad * 8;
    }

    f32x4 acc[4][4];
#pragma unroll
    for (int i = 0; i < 4; ++i)
#pragma unroll
        for (int j = 0; j < 4; ++j)
#pragma unroll
            for (int r = 0; r < 4; ++r) acc[i][j][r] = 0.0f;

    short8x a_cur[4], b_cur[4], a_nxt[4], b_nxt[4];
#pragma unroll
    for (int t = 0; t < 4; ++t) {
        a_cur[t] = *(const short8x*)(arow[t]);
        b_cur[t] = *(const short8x*)(brow[t]);
    }

    for (int k0 = 0; k0 < K; k0 += 32) {
        if (k0 + 32 < K) {
#pragma unroll
            for (int t = 0; t < 4; ++t) {
                a_nxt[t] = *(const short8x*)(arow[t] + k0 + 32);
                b_nxt[t] = *(const short8x*)(brow[t] + k0 + 32);
            }
        }
#pragma unroll
        for (int mt = 0; mt < 4; ++mt)
#pragma unroll
            for (int nt = 0; nt < 4; ++nt)
                acc[mt][nt] = __builtin_amdgcn_mfma_f32_16x16x32_bf16(
                    a_cur[mt], b_cur[nt], acc[mt][nt], 0, 0, 0);
#pragma unroll
        for (int t = 0; t < 4; ++t) { a_cur[t] = a_nxt[t]; b_cur[t] = b_nxt[t]; }
    }

    // epilogue: C/D layout col=lane&15, row=quad*4+r
#pragma unroll
    for (int mt = 0; mt < 4; ++mt) {
#pragma unroll
        for (int r = 0; r < 4; ++r) {
            int row = m0 + mt * 16 + quad * 4 + r;
            if (row < M) {
#pragma unroll
                for (int nt = 0; nt < 4; ++nt) {
                    int col = n0 + nt * 16 + c16;
                    Cb[(size_t)row * Npad + col] = f2bf(acc[mt][nt][r]);
                }
            }
        }
    }
}

// ---------------------------------------------------------------------------
// attention logits from bf16 xp (packed pairs, row stride ldp uints).
// block=256; group G=256/H.
// ---------------------------------------------------------------------------
__global__ __launch_bounds__(256) void logits_bf16_kernel(
    const uint_t* __restrict__ xpb,     // [node][ldp] packed 2xbf16
    const float* __restrict__ a_src, const float* __restrict__ a_dst,
    float* __restrict__ s, float* __restrict__ d,
    int H, int C, int Cpair, int ldp)
{
    int node = blockIdx.x;
    int tid = threadIdx.x;
    int G = 256 / H;
    int h = tid / G;
    int cp = tid - h * G;
    float vs = 0.f, vd = 0.f;
    if (cp < Cpair) {
        uint_t p = xpb[(size_t)node * ldp + h * Cpair + cp];
        float f0 = bf_lo(p), f1 = bf_hi(p);
        int c = cp * 2;
        vs = f0 * a_src[h * C + c] + f1 * a_src[h * C + c + 1];
        vd = f0 * a_dst[h * C + c] + f1 * a_dst[h * C + c + 1];
    }
    __shared__ float rs[256];
    __shared__ float rd[256];
    rs[tid] = vs; rd[tid] = vd;
    __syncthreads();
    for (int off = G >> 1; off > 0; off >>= 1) {
        if (cp < off) { rs[tid] += rs[tid + off]; rd[tid] += rd[tid + off]; }
        __syncthreads();
    }
    if (cp == 0) { s[node * H + h] = rs[tid]; d[node * H + h] = rd[tid]; }
}

// ---------------------------------------------------------------------------
// scalar softmax over each dst's edge list: one wave per dst node.
// ---------------------------------------------------------------------------
template<int H>
__global__ __launch_bounds__(64) void edge_softmax_kernel(
    const float* __restrict__ s,     // [node][H]
    const float* __restrict__ dlog,  // [node][H]
    const int* __restrict__ offsets, const int* __restrict__ esrc,
    float* __restrict__ ew,          // [E][H] unnormalized exp weights
    float* __restrict__ wself,       // [node][H]
    float* __restrict__ zinv)        // [node][H]
{
    int dst = blockIdx.x;
    int lane = threadIdx.x;
    int e0 = offsets[dst], e1 = offsets[dst + 1];

    float dh[H], selfe[H], mh[H], zh[H];
#pragma unroll
    for (int h = 0; h < H; ++h) {
        dh[h] = dlog[dst * H + h];
        selfe[h] = lrelu(s[dst * H + h] + dh[h]);
        mh[h] = selfe[h];
        zh[h] = 0.f;
    }

    // pass 1: max
    for (int j = e0 + lane; j < e1; j += 64) {
        int src = esrc[j];
        if (H == 4) {
            float4 sv = ((const float4*)s)[src];
            mh[0] = fmaxf(mh[0], lrelu(sv.x + dh[0]));
            mh[1] = fmaxf(mh[1], lrelu(sv.y + dh[1]));
            mh[2] = fmaxf(mh[2], lrelu(sv.z + dh[2]));
            mh[3] = fmaxf(mh[3], lrelu(sv.w + dh[3]));
        } else {
#pragma unroll
            for (int h = 0; h < H; ++h)
                mh[h] = fmaxf(mh[h], lrelu(s[src * H + h] + dh[h]));
        }
    }
#pragma unroll
    for (int h = 0; h < H; ++h)
        for (int off = 32; off > 0; off >>= 1)
            mh[h] = fmaxf(mh[h], __shfl_xor(mh[h], off));

    // pass 2: w = exp(e - m), store, sum
    for (int j = e0 + lane; j < e1; j += 64) {
        int src = esrc[j];
        if (H == 4) {
            float4 sv = ((const float4*)s)[src];
            float w0 = __expf(lrelu(sv.x + dh[0]) - mh[0]);
            float w1 = __expf(lrelu(sv.y + dh[1]) - mh[1]);
            float w2 = __expf(lrelu(sv.z + dh[2]) - mh[2]);
            float w3 = __expf(lrelu(sv.w + dh[3]) - mh[3]);
            ((float4*)ew)[j] = make_float4(w0, w1, w2, w3);
            zh[0] += w0; zh[1] += w1; zh[2] += w2; zh[3] += w3;
        } else {
#pragma unroll
            for (int h = 0; h < H; ++h) {
                float w = __expf(lrelu(s[src * H + h] + dh[h]) - mh[h]);
                ew[(size_t)j * H + h] = w;
                zh[h] += w;
            }
        }
    }
#pragma unroll
    for (int h = 0; h < H; ++h)
        for (int off = 32; off > 0; off >>= 1)
            zh[h] += __shfl_xor(zh[h], off);

    if (lane == 0) {
#pragma unroll
        for (int h = 0; h < H; ++h) {
            float ws = __expf(selfe[h] - mh[h]);
            wself[dst * H + h] = ws;
            zinv[dst * H + h] = 1.0f / (zh[h] + ws);
        }
    }
}

// ---------------------------------------------------------------------------
// weighted gather-aggregate, wave-per-node, uint4 (16B/lane = 1KB/row/inst).
// xpb4: [node][64] uint4 (row = 512 bf16 = 1KB; layer-3 rows zero-padded).
// Each lane owns 8 consecutive channels. 4 waves (4 nodes) per block.
// ---------------------------------------------------------------------------
__device__ __forceinline__ void acc8(float* acc, uint4 q, float w) {
    acc[0] += w * bf_lo(q.x); acc[1] += w * bf_hi(q.x);
    acc[2] += w * bf_lo(q.y); acc[3] += w * bf_hi(q.y);
    acc[4] += w * bf_lo(q.z); acc[5] += w * bf_hi(q.z);
    acc[6] += w * bf_lo(q.w); acc[7] += w * bf_hi(q.w);
}

template<int H>
__global__ __launch_bounds__(256) void aggregate3_kernel(
    const uint4* __restrict__ xpb4,     // [node][64]
    const int* __restrict__ offsets, const int* __restrict__ esrc,
    const float* __restrict__ ew,       // [E][H]
    const float* __restrict__ wself,    // [node][H]
    const float* __restrict__ zinv,     // [node][H]
    const float* __restrict__ bias,     // [OUTC]
    float* __restrict__ out,            // [node][ldo]
    int OUTC, int ldo)
{
    int node = blockIdx.x * 4 + (threadIdx.x >> 6);
    if (node >= NNODES) return;
    int lane = threadIdx.x & 63;
    int h = (H == 4) ? (lane >> 4) : 0;   // 8 ch/lane, 128 ch/head

    float ws = wself[node * H + h];
    uint4 p = xpb4[(size_t)node * 64 + lane];
    float acc[8];
    acc[0] = ws * bf_lo(p.x); acc[1] = ws * bf_hi(p.x);
    acc[2] = ws * bf_lo(p.y); acc[3] = ws * bf_hi(p.y);
    acc[4] = ws * bf_lo(p.z); acc[5] = ws * bf_hi(p.z);
    acc[6] = ws * bf_lo(p.w); acc[7] = ws * bf_hi(p.w);

    int e0 = offsets[node], e1 = offsets[node + 1];
    int j = e0;
    for (; j + 3 < e1; j += 4) {
        int s0 = esrc[j], s1 = esrc[j + 1], s2 = esrc[j + 2], s3 = esrc[j + 3];
        float w0 = ew[(size_t)j * H + h];
        float w1 = ew[(size_t)(j + 1) * H + h];
        float w2 = ew[(size_t)(j + 2) * H + h];
        float w3 = ew[(size_t)(j + 3) * H + h];
        uint4 q0 = xpb4[(size_t)s0 * 64 + lane];
        uint4 q1 = xpb4[(size_t)s1 * 64 + lane];
        uint4 q2 = xpb4[(size_t)s2 * 64 + lane];
        uint4 q3 = xpb4[(size_t)s3 * 64 + lane];
        acc8(acc, q0, w0);
        acc8(acc, q1, w1);
        acc8(acc, q2, w2);
        acc8(acc, q3, w3);
    }
    for (; j < e1; ++j) {
        int s0 = esrc[j];
        float w0 = ew[(size_t)j * H + h];
        uint4 q0 = xpb4[(size_t)s0 * 64 + lane];
        acc8(acc, q0, w0);
    }

    float zi = zinv[node * H + h];
    int cbase = lane * 8;
    size_t ob = (size_t)node * ldo + cbase;
    if (cbase + 7 < OUTC) {
        float4 o0 = make_float4(acc[0] * zi + bias[cbase + 0], acc[1] * zi + bias[cbase + 1],
                                acc[2] * zi + bias[cbase + 2], acc[3] * zi + bias[cbase + 3]);
        float4 o1 = make_float4(acc[4] * zi + bias[cbase + 4], acc[5] * zi + bias[cbase + 5],
                                acc[6] * zi + bias[cbase + 6], acc[7] * zi + bias[cbase + 7]);
        *(float4*)(out + ob) = o0;
        *(float4*)(out + ob + 4) = o1;
    } else {
#pragma unroll
        for (int k = 0; k < 8; ++k) {
            int c = cbase + k;
            if (c < OUTC) out[ob + k] = acc[k] * zi + bias[c];
        }
    }
}

// ---------------------------------------------------------------------------
// BatchNorm (training-mode normalization, biased var) + ELU -> bf16
// ---------------------------------------------------------------------------
__global__ __launch_bounds__(512) void bn_stats_kernel(const float* __restrict__ h,
                                                       float* __restrict__ sums,
                                                       float* __restrict__ sumsq,
                                                       int Nrows, int Ncols) {
    int c = threadIdx.x;  // Ncols == 512 == blockDim
    float sm = 0.f, sq = 0.f;
    for (int r = blockIdx.x; r < Nrows; r += gridDim.x) {
        float v = h[(size_t)r * Ncols + c];
        sm += v;
        sq += v * v;
    }
    atomicAdd(&sums[c], sm);
    atomicAdd(&sumsq[c], sq);
}

__global__ __launch_bounds__(512) void bn_finalize_kernel(const float* __restrict__ sums,
                                                          const float* __restrict__ sumsq,
                                                          const float* __restrict__ gamma,
                                                          const float* __restrict__ beta,
                                                          float* __restrict__ scale,
                                                          float* __restrict__ shift,
                                                          int Nrows, int Ncols) {
    int c = threadIdx.x;
    if (c < Ncols) {
        float mu = sums[c] / (float)Nrows;
        float var = sumsq[c] / (float)Nrows - mu * mu;
        float sc = gamma[c] * rsqrtf(var + BN_EPS);
        scale[c] = sc;
        shift[c] = beta[c] - mu * sc;
    }
}

// h fp32 [N][512] -> hbf packed bf16 pairs [N][256]
__global__ void bn_apply_elu_bf16_kernel(const float* __restrict__ h,
                                         const float* __restrict__ scale,
                                         const float* __restrict__ shift,
                                         uint_t* __restrict__ hbf,
                                         int npairs) {
    int i = blockIdx.x * blockDim.x + threadIdx.x;
    if (i < npairs) {
        int c0 = (i & 255) * 2;   // Ncols = 512
        float2 hv = ((const float2*)h)[i];
        float v0 = hv.x * scale[c0]     + shift[c0];
        float v1 = hv.y * scale[c0 + 1] + shift[c0 + 1];
        v0 = (v0 > 0.f) ? v0 : (__expf(v0) - 1.0f);
        v1 = (v1 > 0.f) ? v1 : (__expf(v1) - 1.0f);
        hbf[i] = ((uint_t)f2bf(v1) << 16) | (uint_t)f2bf(v0);
    }
}

// ---------------------------------------------------------------------------
// launch
// ---------------------------------------------------------------------------
extern "C" void kernel_launch(void* const* d_in, const int* in_sizes, int n_in,
                              void* d_out, int out_size, void* d_ws, size_t ws_size,
                              hipStream_t stream) {
    const float* x      = (const float*)d_in[0];
    const int*   ei     = (const int*)d_in[1];
    const float* W1     = (const float*)d_in[2];
    const float* a_src1 = (const float*)d_in[3];
    const float* a_dst1 = (const float*)d_in[4];
    const float* b1     = (const float*)d_in[5];
    const float* g1     = (const float*)d_in[6];
    const float* be1    = (const float*)d_in[7];
    const float* W2     = (const float*)d_in[8];
    const float* a_src2 = (const float*)d_in[9];
    const float* a_dst2 = (const float*)d_in[10];
    const float* b2     = (const float*)d_in[11];
    const float* g2     = (const float*)d_in[12];
    const float* be2    = (const float*)d_in[13];
    const float* W3     = (const float*)d_in[14];
    const float* a_src3 = (const float*)d_in[15];
    const float* a_dst3 = (const float*)d_in[16];
    const float* b3     = (const float*)d_in[17];
    float* out = (float*)d_out;

    const int* e_src = ei;           // edge_index[0]
    const int* e_dst = ei + NEDGES;  // edge_index[1]

    // ---- workspace layout ----
    char* w = (char*)d_ws;
    // region 0: x_bf (25.6 MB), later reused as hbuf fp32 (20.48 MB) + ew (5.12 MB)
    ushort_t* x_bf = (ushort_t*)w;
    float*    hbuf = (float*)w;                               // alias after L1 GEMM
    float*    ew   = (float*)(w + (size_t)NNODES * HC_ * sizeof(float));  // tail 5.12 MB
    w += (size_t)NNODES * INF_ * sizeof(ushort_t);            // 25,600,000
    uint_t* xpb = (uint_t*)w;  w += (size_t)NNODES * HC_ * sizeof(ushort_t);   // 10,240,000
    uint_t* hbf = (uint_t*)w;  w += (size_t)NNODES * HC_ * sizeof(ushort_t);   // 10,240,000
    ushort_t* Wt1 = (ushort_t*)w; w += (size_t)INF_ * HC_ * sizeof(ushort_t);  // 1,310,720
    ushort_t* Wt2 = (ushort_t*)w; w += (size_t)HC_ * HC_ * sizeof(ushort_t);   //   524,288
    ushort_t* Wt3 = (ushort_t*)w; w += (size_t)HC_ * HC_ * sizeof(ushort_t);   //   524,288 (padded 512 rows)
    float* s_log = (float*)w;  w += NNODES * HEADS_ * sizeof(float);
    float* d_log = (float*)w;  w += NNODES * HEADS_ * sizeof(float);
    float* wself = (float*)w;  w += NNODES * HEADS_ * sizeof(float);
    float* zinv  = (float*)w;  w += NNODES * HEADS_ * sizeof(float);
    float* bns   = (float*)w;  w += HC_ * sizeof(float);
    float* bnss  = (float*)w;  w += HC_ * sizeof(float);
    float* bnscale = (float*)w; w += HC_ * sizeof(float);
    float* bnshift = (float*)w; w += HC_ * sizeof(float);
    int* counts  = (int*)w;    w += NNODES * sizeof(int);
    int* offsets = (int*)w;    w += (NNODES + 1) * sizeof(int);
    int* cursor  = (int*)w;    w += NNODES * sizeof(int);
    int* esrc    = (int*)w;    w += NEDGES * sizeof(int);

    // ---- CSR build (once; shared by all 3 layers) ----
    zero_kernel<<<64, 256, 0, stream>>>((float*)counts, NNODES);
    count_kernel<<<(NEDGES + 255) / 256, 256, 0, stream>>>(e_dst, counts, NEDGES);
    scan_kernel<<<1, 1024, 0, stream>>>(counts, offsets, NNODES);
    copy_int_kernel<<<(NNODES + 255) / 256, 256, 0, stream>>>(offsets, cursor, NNODES);
    scatter_kernel<<<(NEDGES + 255) / 256, 256, 0, stream>>>(e_src, e_dst, cursor, esrc, NEDGES);

    // ---- bf16 conversions (x and transposed weights; Wt3 zero-padded to 512 rows) ----
    {
        int nx = NNODES * INF_;
        conv_bf16_kernel<<<(nx + 255) / 256, 256, 0, stream>>>(x, x_bf, nx);
        int n1 = INF_ * HC_;
        transconv_kernel<<<(n1 + 255) / 256, 256, 0, stream>>>(W1, Wt1, INF_, HC_, HC_);
        int n2 = HC_ * HC_;
        transconv_kernel<<<(n2 + 255) / 256, 256, 0, stream>>>(W2, Wt2, HC_, HC_, HC_);
        int n3 = HC_ * HC_;
        transconv_kernel<<<(n3 + 255) / 256, 256, 0, stream>>>(W3, Wt3, HC_, OUTF_, HC_);
    }

    dim3 gb(256);
    dim3 gg(HC_ / 128, (NNODES + 127) / 128);   // (4, 79) for all layers (Npad=512)
    int aggGrid = (NNODES + 3) / 4;

    // ---- Layer 1 ----   (x_bf dead after this GEMM; hbuf/ew alias its region)
    gemm_dg_kernel<<<gg, gb, 0, stream>>>(x_bf, Wt1, (ushort_t*)xpb, NNODES, INF_, HC_);
    logits_bf16_kernel<<<NNODES, 256, 0, stream>>>(xpb, a_src1, a_dst1, s_log, d_log, HEADS_, HID_, HID_ / 2, HC_ / 2);
    edge_softmax_kernel<HEADS_><<<NNODES, 64, 0, stream>>>(s_log, d_log, offsets, esrc, ew, wself, zinv);
    aggregate3_kernel<HEADS_><<<aggGrid, 256, 0, stream>>>((const uint4*)xpb, offsets, esrc, ew, wself, zinv, b1, hbuf, HC_, HC_);
    zero_kernel<<<4, 256, 0, stream>>>(bns, 2 * HC_);
    bn_stats_kernel<<<64, 512, 0, stream>>>(hbuf, bns, bnss, NNODES, HC_);
    bn_finalize_kernel<<<1, 512, 0, stream>>>(bns, bnss, g1, be1, bnscale, bnshift, NNODES, HC_);
    bn_apply_elu_bf16_kernel<<<(NNODES * 256 + 255) / 256, 256, 0, stream>>>(hbuf, bnscale, bnshift, hbf, NNODES * 256);

    // ---- Layer 2 ----
    gemm_dg_kernel<<<gg, gb, 0, stream>>>((const ushort_t*)hbf, Wt2, (ushort_t*)xpb, NNODES, HC_, HC_);
    logits_bf16_kernel<<<NNODES, 256, 0, stream>>>(xpb, a_src2, a_dst2, s_log, d_log, HEADS_, HID_, HID_ / 2, HC_ / 2);
    edge_softmax_kernel<HEADS_><<<NNODES, 64, 0, stream>>>(s_log, d_log, offsets, esrc, ew, wself, zinv);
    aggregate3_kernel<HEADS_><<<aggGrid, 256, 0, stream>>>((const uint4*)xpb, offsets, esrc, ew, wself, zinv, b2, hbuf, HC_, HC_);
    zero_kernel<<<4, 256, 0, stream>>>(bns, 2 * HC_);
    bn_stats_kernel<<<64, 512, 0, stream>>>(hbuf, bns, bnss, NNODES, HC_);
    bn_finalize_kernel<<<1, 512, 0, stream>>>(bns, bnss, g2, be2, bnscale, bnshift, NNODES, HC_);
    bn_apply_elu_bf16_kernel<<<(NNODES * 256 + 255) / 256, 256, 0, stream>>>(hbuf, bnscale, bnshift, hbf, NNODES * 256);

    // ---- Layer 3 (H=1, C=500; Wt3 zero-padded so xp pad cols are true zeros) ----
    gemm_dg_kernel<<<gg, gb, 0, stream>>>((const ushort_t*)hbf, Wt3, (ushort_t*)xpb, NNODES, HC_, HC_);
    logits_bf16_kernel<<<NNODES, 256, 0, stream>>>(xpb, a_src3, a_dst3, s_log, d_log, 1, OUTF_, OUTF_ / 2, HC_ / 2);
    edge_softmax_kernel<1><<<NNODES, 64, 0, stream>>>(s_log, d_log, offsets, esrc, ew, wself, zinv);
    aggregate3_kernel<1><<<aggGrid, 256, 0, stream>>>((const uint4*)xpb, offsets, esrc, ew, wself, zinv, b3, out, OUTF_, OUTF_);
}

// Round 6
// 552.315 us; speedup vs baseline: 1.1375x; 1.1375x over previous
//
#include <hip/hip_runtime.h>
#include <hip/hip_bf16.h>

// Problem constants (from reference)
#define NNODES 10000
#define NEDGES 320000
#define INF_   1280
#define HID_   128
#define HEADS_ 4
#define OUTF_  500
#define HC_    512          // HEADS_*HID_
#define NEG_SLOPE 0.2f
#define BN_EPS 1e-5f

typedef __attribute__((ext_vector_type(8))) short short8x;
typedef __attribute__((ext_vector_type(4))) float f32x4;
typedef unsigned short ushort_t;
typedef unsigned int uint_t;

__device__ __forceinline__ ushort_t f2bf(float f) {
    uint_t u = __float_as_uint(f);
    u = (u + 0x7fffu + ((u >> 16) & 1u)) >> 16;   // round-to-nearest-even
    return (ushort_t)u;
}
__device__ __forceinline__ float bf_lo(uint_t p) { return __uint_as_float(p << 16); }
__device__ __forceinline__ float bf_hi(uint_t p) { return __uint_as_float(p & 0xffff0000u); }
__device__ __forceinline__ float lrelu(float x) { return (x >= 0.f) ? x : NEG_SLOPE * x; }

// ---------------------------------------------------------------------------
// utility kernels
// ---------------------------------------------------------------------------
__global__ void zero_kernel(float* __restrict__ p, size_t n) {
    size_t i = (size_t)blockIdx.x * blockDim.x + threadIdx.x;
    size_t stride = (size_t)gridDim.x * blockDim.x;
    for (; i < n; i += stride) p[i] = 0.0f;
}

// fp32 -> bf16 (flat)
__global__ void conv_bf16_kernel(const float* __restrict__ in, ushort_t* __restrict__ out, int n) {
    int i = blockIdx.x * blockDim.x + threadIdx.x;
    if (i < n) out[i] = f2bf(in[i]);
}

// fp32 W[K][N] -> bf16 Wt[Npad][K]  (write-coalesced; rows [N,Npad) zeroed)
__global__ void transconv_kernel(const float* __restrict__ W, ushort_t* __restrict__ Wt,
                                 int K, int N, int Npad) {
    int i = blockIdx.x * blockDim.x + threadIdx.x;
    if (i < Npad * K) {
        int n = i / K;
        int k = i - n * K;
        Wt[i] = (n < N) ? f2bf(W[(size_t)k * N + n]) : (ushort_t)0;
    }
}

// ---------------------------------------------------------------------------
// CSR build (by destination) — hierarchical scan, built once per call
// ---------------------------------------------------------------------------
__global__ void count_kernel(const int* __restrict__ dst, int* __restrict__ counts, int E) {
    int e = blockIdx.x * blockDim.x + threadIdx.x;
    if (e < E) atomicAdd(&counts[dst[e]], 1);
}

// phase 1: per-256 block exclusive scan (no base), block sums out
__global__ __launch_bounds__(256) void scan1_kernel(const int* __restrict__ counts,
                                                    int* __restrict__ offsets,
                                                    int* __restrict__ bsum, int n) {
    __shared__ int tmp[256];
    int b = blockIdx.x, t = threadIdx.x;
    int i = b * 256 + t;
    int v = (i < n) ? counts[i] : 0;
    tmp[t] = v;
    __syncthreads();
    for (int off = 1; off < 256; off <<= 1) {
        int u = (t >= off) ? tmp[t - off] : 0;
        __syncthreads();
        tmp[t] += u;
        __syncthreads();
    }
    if (i < n) offsets[i] = tmp[t] - v;
    if (t == 255) bsum[b] = tmp[t];
}

// phase 2: serial exclusive scan of 40 block sums (tiny)
__global__ void scan2_kernel(const int* __restrict__ bsum, int* __restrict__ bbase,
                             int* __restrict__ offsets, int nb, int n) {
    if (threadIdx.x == 0) {
        int acc = 0;
        for (int b = 0; b < nb; ++b) { bbase[b] = acc; acc += bsum[b]; }
        offsets[n] = acc;
    }
}

// phase 3: add block bases; also produce cursor copy for scatter
__global__ void scan3_kernel(int* __restrict__ offsets, int* __restrict__ cursor,
                             const int* __restrict__ bbase, int n) {
    int i = blockIdx.x * 256 + threadIdx.x;
    if (i < n) {
        int v = offsets[i] + bbase[i >> 8];
        offsets[i] = v;
        cursor[i] = v;
    }
}

__global__ void scatter_kernel(const int* __restrict__ src, const int* __restrict__ dst,
                               int* __restrict__ cursor, int* __restrict__ esrc, int E) {
    int e = blockIdx.x * blockDim.x + threadIdx.x;
    if (e < E) {
        int p = atomicAdd(&cursor[dst[e]], 1);
        esrc[p] = src[e];
    }
}

// ---------------------------------------------------------------------------
// bf16 MFMA GEMM with fused attention-logit epilogue.
//   C[M,512] = A[M,K] @ Bt[512,K]^T (bf16 out, row stride 512, pad cols zero
//   via zero-padded Bt rows). 64x64 tile, BK=32, 256 thr = 4 waves (2x2).
//   1-D grid, XCD-swizzled: all 8 col-blocks of a row-block share id%8 so
//   they land on one XCD and A stays L2-resident (id%8 -> XCD heuristic).
//   Epilogue: s[row,h] += sum_col acc*a_src[col] (shfl-reduce + atomicAdd),
//   same for d — replaces the standalone logits kernel.
// ---------------------------------------------------------------------------
#define LDT 40   // LDS row stride in bf16 units (padded; 80B keeps 16B align)

__global__ __launch_bounds__(256) void gemm_fused_kernel(
    const ushort_t* __restrict__ A,    // [M][K] bf16
    const ushort_t* __restrict__ Bt,   // [512][K] bf16 (transposed, padded)
    ushort_t* __restrict__ Cb,         // [M][512] bf16
    const float* __restrict__ avS,     // a_src flat [N]
    const float* __restrict__ avD,     // a_dst flat [N]
    float* __restrict__ s_log,         // [M][H] (pre-zeroed)
    float* __restrict__ d_log,         // [M][H]
    int M, int K, int N, int H, int nRB)
{
    __shared__ __align__(16) ushort_t As[64 * LDT];
    __shared__ __align__(16) ushort_t Bs[64 * LDT];

    // swizzle: ib = g*8 + (id&7), j = (id>>3)&7  -> col-blocks share XCD
    int id = blockIdx.x;
    int ib = (id >> 6) * 8 + (id & 7);
    int j  = (id >> 3) & 7;
    if (ib >= nRB) return;
    int m0 = ib * 64, n0 = j * 64;

    int tid  = threadIdx.x;
    int lane = tid & 63;
    int w    = tid >> 6;
    int wm   = (w & 1) * 32;
    int wn   = (w >> 1) * 32;
    int quad = lane >> 4;
    int c16  = lane & 15;

    f32x4 acc[2][2];
#pragma unroll
    for (int i = 0; i < 2; ++i)
#pragma unroll
        for (int jj = 0; jj < 2; ++jj)
#pragma unroll
            for (int r = 0; r < 4; ++r) acc[i][jj][r] = 0.0f;

    int sr = tid >> 2;          // 0..63 row within tile
    int sk = (tid & 3) * 8;     // k chunk: 0,8,16,24

    for (int k0 = 0; k0 < K; k0 += 32) {
        uint4 av = make_uint4(0, 0, 0, 0);
        int gm = m0 + sr;
        if (gm < M) av = *(const uint4*)(A + (size_t)gm * K + k0 + sk);
        *(uint4*)&As[sr * LDT + sk] = av;

        // Bt always has 512 valid rows (zero-padded) -> no guard
        uint4 bv = *(const uint4*)(Bt + (size_t)(n0 + sr) * K + k0 + sk);
        *(uint4*)&Bs[sr * LDT + sk] = bv;
        __syncthreads();

        short8x af0 = *(const short8x*)&As[(wm +      c16) * LDT + quad * 8];
        short8x af1 = *(const short8x*)&As[(wm + 16 + c16) * LDT + quad * 8];
        short8x bf0 = *(const short8x*)&Bs[(wn +      c16) * LDT + quad * 8];
        short8x bf1 = *(const short8x*)&Bs[(wn + 16 + c16) * LDT + quad * 8];

        acc[0][0] = __builtin_amdgcn_mfma_f32_16x16x32_bf16(af0, bf0, acc[0][0], 0, 0, 0);
        acc[0][1] = __builtin_amdgcn_mfma_f32_16x16x32_bf16(af0, bf1, acc[0][1], 0, 0, 0);
        acc[1][0] = __builtin_amdgcn_mfma_f32_16x16x32_bf16(af1, bf0, acc[1][0], 0, 0, 0);
        acc[1][1] = __builtin_amdgcn_mfma_f32_16x16x32_bf16(af1, bf1, acc[1][1], 0, 0, 0);
        __syncthreads();
    }

    // ---- epilogue: C store + logit partials ----
    int col0 = n0 + wn + c16;
    int col1 = col0 + 16;
    float as0 = (col0 < N) ? avS[col0] : 0.f;
    float as1 = (col1 < N) ? avS[col1] : 0.f;
    float ad0 = (col0 < N) ? avD[col0] : 0.f;
    float ad1 = (col1 < N) ? avD[col1] : 0.f;

    float sv[8], dv[8];   // [mt*4+r]
#pragma unroll
    for (int mt = 0; mt < 2; ++mt) {
#pragma unroll
        for (int r = 0; r < 4; ++r) {
            float v0 = acc[mt][0][r];
            float v1 = acc[mt][1][r];
            sv[mt * 4 + r] = v0 * as0 + v1 * as1;
            dv[mt * 4 + r] = v0 * ad0 + v1 * ad1;
            int row = m0 + wm + mt * 16 + quad * 4 + r;
            if (row < M) {
                Cb[(size_t)row * 512 + col0] = f2bf(v0);
                Cb[(size_t)row * 512 + col1] = f2bf(v1);
            }
        }
    }
    // reduce over the 16 c16 lanes (stays within 16-lane group for off<16)
#pragma unroll
    for (int off = 1; off < 16; off <<= 1) {
#pragma unroll
        for (int i = 0; i < 8; ++i) {
            sv[i] += __shfl_xor(sv[i], off);
            dv[i] += __shfl_xor(dv[i], off);
        }
    }
    if (c16 == 0) {
        int hb = (H == 4) ? (n0 >> 7) : 0;
#pragma unroll
        for (int mt = 0; mt < 2; ++mt) {
#pragma unroll
            for (int r = 0; r < 4; ++r) {
                int row = m0 + wm + mt * 16 + quad * 4 + r;
                if (row < M) {
                    atomicAdd(&s_log[row * H + hb], sv[mt * 4 + r]);
                    atomicAdd(&d_log[row * H + hb], dv[mt * 4 + r]);
                }
            }
        }
    }
}

// ---------------------------------------------------------------------------
// scalar softmax over each dst's edge list: one wave per dst node.
// ---------------------------------------------------------------------------
template<int H>
__global__ __launch_bounds__(64) void edge_softmax_kernel(
    const float* __restrict__ s,     // [node][H]
    const float* __restrict__ dlog,  // [node][H]
    const int* __restrict__ offsets, const int* __restrict__ esrc,
    float* __restrict__ ew,          // [E][H] unnormalized exp weights
    float* __restrict__ wself,       // [node][H]
    float* __restrict__ zinv)        // [node][H]
{
    int dst = blockIdx.x;
    int lane = threadIdx.x;
    int e0 = offsets[dst], e1 = offsets[dst + 1];

    float dh[H], selfe[H], mh[H], zh[H];
#pragma unroll
    for (int h = 0; h < H; ++h) {
        dh[h] = dlog[dst * H + h];
        selfe[h] = lrelu(s[dst * H + h] + dh[h]);
        mh[h] = selfe[h];
        zh[h] = 0.f;
    }

    // pass 1: max
    for (int j = e0 + lane; j < e1; j += 64) {
        int src = esrc[j];
        if (H == 4) {
            float4 sv = ((const float4*)s)[src];
            mh[0] = fmaxf(mh[0], lrelu(sv.x + dh[0]));
            mh[1] = fmaxf(mh[1], lrelu(sv.y + dh[1]));
            mh[2] = fmaxf(mh[2], lrelu(sv.z + dh[2]));
            mh[3] = fmaxf(mh[3], lrelu(sv.w + dh[3]));
        } else {
#pragma unroll
            for (int h = 0; h < H; ++h)
                mh[h] = fmaxf(mh[h], lrelu(s[src * H + h] + dh[h]));
        }
    }
#pragma unroll
    for (int h = 0; h < H; ++h)
        for (int off = 32; off > 0; off >>= 1)
            mh[h] = fmaxf(mh[h], __shfl_xor(mh[h], off));

    // pass 2: w = exp(e - m), store, sum
    for (int j = e0 + lane; j < e1; j += 64) {
        int src = esrc[j];
        if (H == 4) {
            float4 sv = ((const float4*)s)[src];
            float w0 = __expf(lrelu(sv.x + dh[0]) - mh[0]);
            float w1 = __expf(lrelu(sv.y + dh[1]) - mh[1]);
            float w2 = __expf(lrelu(sv.z + dh[2]) - mh[2]);
            float w3 = __expf(lrelu(sv.w + dh[3]) - mh[3]);
            ((float4*)ew)[j] = make_float4(w0, w1, w2, w3);
            zh[0] += w0; zh[1] += w1; zh[2] += w2; zh[3] += w3;
        } else {
#pragma unroll
            for (int h = 0; h < H; ++h) {
                float w = __expf(lrelu(s[src * H + h] + dh[h]) - mh[h]);
                ew[(size_t)j * H + h] = w;
                zh[h] += w;
            }
        }
    }
#pragma unroll
    for (int h = 0; h < H; ++h)
        for (int off = 32; off > 0; off >>= 1)
            zh[h] += __shfl_xor(zh[h], off);

    if (lane == 0) {
#pragma unroll
        for (int h = 0; h < H; ++h) {
            float ws = __expf(selfe[h] - mh[h]);
            wself[dst * H + h] = ws;
            zinv[dst * H + h] = 1.0f / (zh[h] + ws);
        }
    }
}

// ---------------------------------------------------------------------------
// weighted gather-aggregate, wave-per-node, uint4 (16B/lane = 1KB/row/inst).
// ---------------------------------------------------------------------------
__device__ __forceinline__ void acc8(float* acc, uint4 q, float w) {
    acc[0] += w * bf_lo(q.x); acc[1] += w * bf_hi(q.x);
    acc[2] += w * bf_lo(q.y); acc[3] += w * bf_hi(q.y);
    acc[4] += w * bf_lo(q.z); acc[5] += w * bf_hi(q.z);
    acc[6] += w * bf_lo(q.w); acc[7] += w * bf_hi(q.w);
}

template<int H>
__global__ __launch_bounds__(256) void aggregate3_kernel(
    const uint4* __restrict__ xpb4,     // [node][64]
    const int* __restrict__ offsets, const int* __restrict__ esrc,
    const float* __restrict__ ew,       // [E][H]
    const float* __restrict__ wself,    // [node][H]
    const float* __restrict__ zinv,     // [node][H]
    const float* __restrict__ bias,     // [OUTC]
    float* __restrict__ out,            // [node][ldo]
    int OUTC, int ldo)
{
    int node = blockIdx.x * 4 + (threadIdx.x >> 6);
    if (node >= NNODES) return;
    int lane = threadIdx.x & 63;
    int h = (H == 4) ? (lane >> 4) : 0;   // 8 ch/lane, 128 ch/head

    float ws = wself[node * H + h];
    uint4 p = xpb4[(size_t)node * 64 + lane];
    float acc[8];
    acc[0] = ws * bf_lo(p.x); acc[1] = ws * bf_hi(p.x);
    acc[2] = ws * bf_lo(p.y); acc[3] = ws * bf_hi(p.y);
    acc[4] = ws * bf_lo(p.z); acc[5] = ws * bf_hi(p.z);
    acc[6] = ws * bf_lo(p.w); acc[7] = ws * bf_hi(p.w);

    int e0 = offsets[node], e1 = offsets[node + 1];
    int j = e0;
    for (; j + 3 < e1; j += 4) {
        int s0 = esrc[j], s1 = esrc[j + 1], s2 = esrc[j + 2], s3 = esrc[j + 3];
        float w0 = ew[(size_t)j * H + h];
        float w1 = ew[(size_t)(j + 1) * H + h];
        float w2 = ew[(size_t)(j + 2) * H + h];
        float w3 = ew[(size_t)(j + 3) * H + h];
        uint4 q0 = xpb4[(size_t)s0 * 64 + lane];
        uint4 q1 = xpb4[(size_t)s1 * 64 + lane];
        uint4 q2 = xpb4[(size_t)s2 * 64 + lane];
        uint4 q3 = xpb4[(size_t)s3 * 64 + lane];
        acc8(acc, q0, w0);
        acc8(acc, q1, w1);
        acc8(acc, q2, w2);
        acc8(acc, q3, w3);
    }
    for (; j < e1; ++j) {
        int s0 = esrc[j];
        float w0 = ew[(size_t)j * H + h];
        uint4 q0 = xpb4[(size_t)s0 * 64 + lane];
        acc8(acc, q0, w0);
    }

    float zi = zinv[node * H + h];
    int cbase = lane * 8;
    size_t ob = (size_t)node * ldo + cbase;
    if (cbase + 7 < OUTC) {
        float4 o0 = make_float4(acc[0] * zi + bias[cbase + 0], acc[1] * zi + bias[cbase + 1],
                                acc[2] * zi + bias[cbase + 2], acc[3] * zi + bias[cbase + 3]);
        float4 o1 = make_float4(acc[4] * zi + bias[cbase + 4], acc[5] * zi + bias[cbase + 5],
                                acc[6] * zi + bias[cbase + 6], acc[7] * zi + bias[cbase + 7]);
        *(float4*)(out + ob) = o0;
        *(float4*)(out + ob + 4) = o1;
    } else {
#pragma unroll
        for (int k = 0; k < 8; ++k) {
            int c = cbase + k;
            if (c < OUTC) out[ob + k] = acc[k] * zi + bias[c];
        }
    }
}

// ---------------------------------------------------------------------------
// BatchNorm (training normalization, biased var) + ELU -> bf16
// partial-sum version: no zero-init, no atomics.
// ---------------------------------------------------------------------------
__global__ __launch_bounds__(512) void bn_stats_kernel(const float* __restrict__ h,
                                                       float* __restrict__ psum,
                                                       float* __restrict__ psumsq,
                                                       int Nrows) {
    int c = threadIdx.x;  // 512
    int b = blockIdx.x;   // 64
    float sm = 0.f, sq = 0.f;
    for (int r = b; r < Nrows; r += 64) {
        float v = h[(size_t)r * 512 + c];
        sm += v;
        sq += v * v;
    }
    psum[b * 512 + c] = sm;
    psumsq[b * 512 + c] = sq;
}

__global__ __launch_bounds__(512) void bn_finalize_kernel(const float* __restrict__ psum,
                                                          const float* __restrict__ psumsq,
                                                          const float* __restrict__ gamma,
                                                          const float* __restrict__ beta,
                                                          float* __restrict__ scale,
                                                          float* __restrict__ shift,
                                                          int Nrows) {
    int c = threadIdx.x;
    float sm = 0.f, sq = 0.f;
    for (int b = 0; b < 64; ++b) {
        sm += psum[b * 512 + c];
        sq += psumsq[b * 512 + c];
    }
    float mu = sm / (float)Nrows;
    float var = sq / (float)Nrows - mu * mu;
    float sc = gamma[c] * rsqrtf(var + BN_EPS);
    scale[c] = sc;
    shift[c] = beta[c] - mu * sc;
}

// h fp32 [N][512] -> hbf packed bf16 pairs [N][256]
__global__ void bn_apply_elu_bf16_kernel(const float* __restrict__ h,
                                         const float* __restrict__ scale,
                                         const float* __restrict__ shift,
                                         uint_t* __restrict__ hbf,
                                         int npairs) {
    int i = blockIdx.x * blockDim.x + threadIdx.x;
    if (i < npairs) {
        int c0 = (i & 255) * 2;   // Ncols = 512
        float2 hv = ((const float2*)h)[i];
        float v0 = hv.x * scale[c0]     + shift[c0];
        float v1 = hv.y * scale[c0 + 1] + shift[c0 + 1];
        v0 = (v0 > 0.f) ? v0 : (__expf(v0) - 1.0f);
        v1 = (v1 > 0.f) ? v1 : (__expf(v1) - 1.0f);
        hbf[i] = ((uint_t)f2bf(v1) << 16) | (uint_t)f2bf(v0);
    }
}

// ---------------------------------------------------------------------------
// launch
// ---------------------------------------------------------------------------
extern "C" void kernel_launch(void* const* d_in, const int* in_sizes, int n_in,
                              void* d_out, int out_size, void* d_ws, size_t ws_size,
                              hipStream_t stream) {
    const float* x      = (const float*)d_in[0];
    const int*   ei     = (const int*)d_in[1];
    const float* W1     = (const float*)d_in[2];
    const float* a_src1 = (const float*)d_in[3];
    const float* a_dst1 = (const float*)d_in[4];
    const float* b1     = (const float*)d_in[5];
    const float* g1     = (const float*)d_in[6];
    const float* be1    = (const float*)d_in[7];
    const float* W2     = (const float*)d_in[8];
    const float* a_src2 = (const float*)d_in[9];
    const float* a_dst2 = (const float*)d_in[10];
    const float* b2     = (const float*)d_in[11];
    const float* g2     = (const float*)d_in[12];
    const float* be2    = (const float*)d_in[13];
    const float* W3     = (const float*)d_in[14];
    const float* a_src3 = (const float*)d_in[15];
    const float* a_dst3 = (const float*)d_in[16];
    const float* b3     = (const float*)d_in[17];
    float* out = (float*)d_out;

    const int* e_src = ei;           // edge_index[0]
    const int* e_dst = ei + NEDGES;  // edge_index[1]

    // ---- workspace layout ----
    char* w = (char*)d_ws;
    // region 0: x_bf (25.6 MB), later reused as hbuf fp32 (20.48 MB) + ew (5.12 MB)
    ushort_t* x_bf = (ushort_t*)w;
    float*    hbuf = (float*)w;                               // alias after L1 GEMM
    float*    ew   = (float*)(w + (size_t)NNODES * HC_ * sizeof(float));  // tail 5.12 MB
    w += (size_t)NNODES * INF_ * sizeof(ushort_t);            // 25,600,000
    uint_t* xpb = (uint_t*)w;  w += (size_t)NNODES * HC_ * sizeof(ushort_t);   // 10,240,000
    uint_t* hbf = (uint_t*)w;  w += (size_t)NNODES * HC_ * sizeof(ushort_t);   // 10,240,000
    ushort_t* Wt1 = (ushort_t*)w; w += (size_t)INF_ * HC_ * sizeof(ushort_t);  // 1,310,720
    ushort_t* Wt2 = (ushort_t*)w; w += (size_t)HC_ * HC_ * sizeof(ushort_t);   //   524,288
    ushort_t* Wt3 = (ushort_t*)w; w += (size_t)HC_ * HC_ * sizeof(ushort_t);   //   524,288 (padded 512 rows)
    // counts, s_log, d_log contiguous -> single zero pass
    int* counts  = (int*)w;    w += NNODES * sizeof(int);
    float* s_log = (float*)w;  w += NNODES * HEADS_ * sizeof(float);
    float* d_log = (float*)w;  w += NNODES * HEADS_ * sizeof(float);
    float* wself = (float*)w;  w += NNODES * HEADS_ * sizeof(float);
    float* zinv  = (float*)w;  w += NNODES * HEADS_ * sizeof(float);
    float* bnscale = (float*)w; w += HC_ * sizeof(float);
    float* bnshift = (float*)w; w += HC_ * sizeof(float);
    float* psum  = (float*)w;  w += 64 * HC_ * sizeof(float);
    float* psumsq= (float*)w;  w += 64 * HC_ * sizeof(float);
    int* offsets = (int*)w;    w += (NNODES + 1) * sizeof(int);
    int* cursor  = (int*)w;    w += NNODES * sizeof(int);
    int* esrc    = (int*)w;    w += NEDGES * sizeof(int);
    int* bsum    = (int*)w;    w += 64 * sizeof(int);
    int* bbase   = (int*)w;    w += 64 * sizeof(int);

    const int nRB = (NNODES + 63) / 64;              // 157 row blocks
    const int gemmBlocks = ((nRB + 7) / 8) * 64;     // swizzled 1-D grid (1280)
    int aggGrid = (NNODES + 3) / 4;
    const int scanBlocks = (NNODES + 255) / 256;     // 40

    // ---- CSR build + zero (counts | s_log | d_log share one zero pass) ----
    zero_kernel<<<64, 256, 0, stream>>>((float*)counts, NNODES + 2 * NNODES * HEADS_);
    count_kernel<<<(NEDGES + 255) / 256, 256, 0, stream>>>(e_dst, counts, NEDGES);
    scan1_kernel<<<scanBlocks, 256, 0, stream>>>(counts, offsets, bsum, NNODES);
    scan2_kernel<<<1, 64, 0, stream>>>(bsum, bbase, offsets, scanBlocks, NNODES);
    scan3_kernel<<<scanBlocks, 256, 0, stream>>>(offsets, cursor, bbase, NNODES);
    scatter_kernel<<<(NEDGES + 255) / 256, 256, 0, stream>>>(e_src, e_dst, cursor, esrc, NEDGES);

    // ---- bf16 conversions (x and transposed weights; Wt3 zero-padded) ----
    {
        int nx = NNODES * INF_;
        conv_bf16_kernel<<<(nx + 255) / 256, 256, 0, stream>>>(x, x_bf, nx);
        int n1 = INF_ * HC_;
        transconv_kernel<<<(n1 + 255) / 256, 256, 0, stream>>>(W1, Wt1, INF_, HC_, HC_);
        int n2 = HC_ * HC_;
        transconv_kernel<<<(n2 + 255) / 256, 256, 0, stream>>>(W2, Wt2, HC_, HC_, HC_);
        int n3 = HC_ * HC_;
        transconv_kernel<<<(n3 + 255) / 256, 256, 0, stream>>>(W3, Wt3, HC_, OUTF_, HC_);
    }

    // ---- Layer 1 ----   (x_bf dead after its GEMM; hbuf/ew alias its region)
    gemm_fused_kernel<<<gemmBlocks, 256, 0, stream>>>(x_bf, Wt1, (ushort_t*)xpb,
        a_src1, a_dst1, s_log, d_log, NNODES, INF_, HC_, HEADS_, nRB);
    edge_softmax_kernel<HEADS_><<<NNODES, 64, 0, stream>>>(s_log, d_log, offsets, esrc, ew, wself, zinv);
    aggregate3_kernel<HEADS_><<<aggGrid, 256, 0, stream>>>((const uint4*)xpb, offsets, esrc, ew, wself, zinv, b1, hbuf, HC_, HC_);
    bn_stats_kernel<<<64, 512, 0, stream>>>(hbuf, psum, psumsq, NNODES);
    bn_finalize_kernel<<<1, 512, 0, stream>>>(psum, psumsq, g1, be1, bnscale, bnshift, NNODES);
    bn_apply_elu_bf16_kernel<<<(NNODES * 256 + 255) / 256, 256, 0, stream>>>(hbuf, bnscale, bnshift, hbf, NNODES * 256);

    // ---- Layer 2 ----
    zero_kernel<<<32, 256, 0, stream>>>(s_log, 2 * NNODES * HEADS_);
    gemm_fused_kernel<<<gemmBlocks, 256, 0, stream>>>((const ushort_t*)hbf, Wt2, (ushort_t*)xpb,
        a_src2, a_dst2, s_log, d_log, NNODES, HC_, HC_, HEADS_, nRB);
    edge_softmax_kernel<HEADS_><<<NNODES, 64, 0, stream>>>(s_log, d_log, offsets, esrc, ew, wself, zinv);
    aggregate3_kernel<HEADS_><<<aggGrid, 256, 0, stream>>>((const uint4*)xpb, offsets, esrc, ew, wself, zinv, b2, hbuf, HC_, HC_);
    bn_stats_kernel<<<64, 512, 0, stream>>>(hbuf, psum, psumsq, NNODES);
    bn_finalize_kernel<<<1, 512, 0, stream>>>(psum, psumsq, g2, be2, bnscale, bnshift, NNODES);
    bn_apply_elu_bf16_kernel<<<(NNODES * 256 + 255) / 256, 256, 0, stream>>>(hbuf, bnscale, bnshift, hbf, NNODES * 256);

    // ---- Layer 3 (H=1, N=500; Wt3 zero-padded so xp pad cols are true zeros) ----
    zero_kernel<<<32, 256, 0, stream>>>(s_log, 2 * NNODES * HEADS_);
    gemm_fused_kernel<<<gemmBlocks, 256, 0, stream>>>((const ushort_t*)hbf, Wt3, (ushort_t*)xpb,
        a_src3, a_dst3, s_log, d_log, NNODES, HC_, OUTF_, 1, nRB);
    edge_softmax_kernel<1><<<NNODES, 64, 0, stream>>>(s_log, d_log, offsets, esrc, ew, wself, zinv);
    aggregate3_kernel<1><<<aggGrid, 256, 0, stream>>>((const uint4*)xpb, offsets, esrc, ew, wself, zinv, b3, out, OUTF_, OUTF_);
}